// Round 4
// baseline (160.507 us; speedup 1.0000x reference)
//
#include <hip/hip_runtime.h>
#include <cstdint>
#include <cstddef>

#define KCAT  384
#define AST   392            // padded LDS A-row stride (elems): 784B -> 2-way banking (free)
#define NPB   64             // nodes per fused block

typedef __attribute__((ext_vector_type(8))) short bf16x8;
typedef __attribute__((ext_vector_type(4))) float f32x4;

// f32 -> bf16 (round to nearest even), bit-level (inputs are finite)
static __device__ __forceinline__ unsigned short f2bf(float f) {
    unsigned int u = __builtin_bit_cast(unsigned int, f);
    unsigned int lsb = (u >> 16) & 1u;
    u += 0x7fffu + lsb;
    return (unsigned short)(u >> 16);
}
static __device__ __forceinline__ float bfhi(unsigned int u) {  // high bf16 -> f32
    return __builtin_bit_cast(float, u & 0xFFFF0000u);
}
static __device__ __forceinline__ float bflo(unsigned int u) {  // low bf16 -> f32
    return __builtin_bit_cast(float, u << 16);
}
static __device__ __forceinline__ void acc8(float* a, const uint4& v) {
    a[0] += bflo(v.x); a[1] += bfhi(v.x); a[2] += bflo(v.y); a[3] += bfhi(v.y);
    a[4] += bflo(v.z); a[5] += bfhi(v.z); a[6] += bflo(v.w); a[7] += bfhi(v.w);
}

// ---------------- Kernel 0: V[o][k] = concat(Wg,Wl,Ws)[o][k] in bf16 ----------------
__global__ void build_V(const float* __restrict__ Wg, const float* __restrict__ Wl,
                        const float* __restrict__ Ws, unsigned short* __restrict__ V) {
    const int o = blockIdx.x;     // 128 blocks
    const int k = threadIdx.x;    // 384 threads
    float v;
    if (k < 128)      v = Wg[o * 128 + k];
    else if (k < 256) v = Wl[o * 128 + (k - 128)];
    else              v = Ws[o * 128 + (k - 256)];
    V[o * KCAT + k] = f2bf(v);
}

// ---------------- Kernel 0b: xb = bf16(x). one thread per 8 elems ----------------
__global__ __launch_bounds__(256)
void convert_x(const float* __restrict__ x, unsigned short* __restrict__ xb, int total8) {
    int gid = blockIdx.x * 256 + threadIdx.x;
    if (gid >= total8) return;
    const float4* px = (const float4*)x + (size_t)gid * 2;
    float4 a = px[0], bq = px[1];
    uint4 u;
    u.x = (unsigned)f2bf(a.x)  | ((unsigned)f2bf(a.y)  << 16);
    u.y = (unsigned)f2bf(a.z)  | ((unsigned)f2bf(a.w)  << 16);
    u.z = (unsigned)f2bf(bq.x) | ((unsigned)f2bf(bq.y) << 16);
    u.w = (unsigned)f2bf(bq.z) | ((unsigned)f2bf(bq.w) << 16);
    ((uint4*)xb)[gid] = u;
}

// ---------------- Fused: gather-mean -> LDS A-panel -> MFMA GEMM -> ELU ----------------
// 512 threads = 8 waves, 64 nodes/block. Phase 1: wave wv computes nodes wv*8..wv*8+7:
// mean over <=32 edges (idx via one coalesced load + shfl; 16 row-loads in flight).
// A-panel row = [x | mask*mean | mask*x] bf16, padded stride 392.
// Phase 2: each wave owns a 32x32 output quadrant; A-frags from LDS (2-way banks, free),
// B-frags direct from L2-resident V (register prefetch, no barriers).
__global__ __launch_bounds__(512, 6)
void fused_agg_gemm(const unsigned short* __restrict__ xb, const int* __restrict__ src,
                    const int* __restrict__ dst, const int* __restrict__ deg,
                    const unsigned short* __restrict__ V, const float* __restrict__ bias,
                    float* __restrict__ out, int N, int E) {
    __shared__ __align__(16) unsigned short Ash[NPB * AST];   // 50176 B
    __shared__ int sstart[NPB];
    __shared__ int sdeg[NPB];
    const int t    = threadIdx.x;
    const int wv   = t >> 6;
    const int lane = t & 63;
    const int c    = lane & 15;          // 16B column
    const int p    = lane >> 4;          // parity 0..3
    const int base = blockIdx.x * NPB;

    if (wv == 0) {
        // block start: one binary search on sorted dst (broadcast loads, amortized over 64 nodes)
        int lo = 0, hi = E;
        while (lo < hi) { int mid = (lo + hi) >> 1; if (dst[mid] < base) lo = mid + 1; else hi = mid; }
        int n  = base + lane;
        int dg = (n < N) ? deg[n] : 0;
        int incl = dg;
#pragma unroll
        for (int off = 1; off < 64; off <<= 1) {
            int v = __shfl_up(incl, off, 64);
            if (lane >= off) incl += v;
        }
        sstart[lane] = lo + incl - dg;
        sdeg[lane]   = dg;
    }
    __syncthreads();

    // ---- Phase 1: gather
    const uint4* x4 = (const uint4*)xb;
    for (int r = 0; r < 8; ++r) {
        const int row = wv * 8 + r;
        const int n   = base + row;
        const int d   = sdeg[row];                 // 0 for n >= N
        const int s   = sstart[row];
        int idx = 0;
        if (lane < d) idx = src[s + lane];         // one coalesced shot, d <= 32
        uint4 xv = {0, 0, 0, 0};
        if (p == 1 && n < N) xv = x4[(size_t)n * 16 + c];

        float a[8] = {0,0,0,0,0,0,0,0};
        float b[8] = {0,0,0,0,0,0,0,0};
        for (int g = 0; g * 16 < d; ++g) {
            int e0 = g * 16 + p;                   // this parity: e0, e0+4, e0+8, e0+12
            int r0 = __shfl(idx, e0, 64);
            int r1 = __shfl(idx, e0 + 4, 64);
            int r2 = __shfl(idx, e0 + 8, 64);
            int r3 = __shfl(idx, e0 + 12, 64);
            uint4 v0 = x4[(size_t)r0 * 16 + c];
            uint4 v1 = x4[(size_t)r1 * 16 + c];
            uint4 v2 = x4[(size_t)r2 * 16 + c];
            uint4 v3 = x4[(size_t)r3 * 16 + c];
            if (e0 < d)      acc8(a, v0);
            if (e0 + 4 < d)  acc8(b, v1);
            if (e0 + 8 < d)  acc8(a, v2);
            if (e0 + 12 < d) acc8(b, v3);
        }
#pragma unroll
        for (int i = 0; i < 8; ++i) a[i] += b[i];
#pragma unroll
        for (int i = 0; i < 8; ++i) {
            a[i] += __shfl_xor(a[i], 16, 64);
            a[i] += __shfl_xor(a[i], 32, 64);
        }
        unsigned short* arow = Ash + row * AST;
        if (p == 0) {
            float inv = (d > 0) ? 1.0f / (float)d : 0.0f;
            uint4 u;
            u.x = (unsigned)f2bf(a[0]*inv) | ((unsigned)f2bf(a[1]*inv) << 16);
            u.y = (unsigned)f2bf(a[2]*inv) | ((unsigned)f2bf(a[3]*inv) << 16);
            u.z = (unsigned)f2bf(a[4]*inv) | ((unsigned)f2bf(a[5]*inv) << 16);
            u.w = (unsigned)f2bf(a[6]*inv) | ((unsigned)f2bf(a[7]*inv) << 16);
            *(uint4*)(arow + 128 + c * 8) = u;
        } else if (p == 1) {
            *(uint4*)(arow + c * 8) = xv;
            uint4 z = xv;
            if (d == 0) { z.x = 0; z.y = 0; z.z = 0; z.w = 0; }
            *(uint4*)(arow + 256 + c * 8) = z;
        }
    }
    __syncthreads();

    // ---- Phase 2: 64x128 GEMM, wave quadrant 32x32 (2x2 grid of 16x16x32 MFMAs)
    const int wrow = (wv >> 2) * 32;
    const int wcol = (wv & 3) * 32;
    const int quad = lane >> 4;
    const unsigned short* V0 = V + (size_t)(wcol + c) * KCAT + quad * 8;
    const unsigned short* V1 = V + (size_t)(wcol + 16 + c) * KCAT + quad * 8;

    f32x4 acc[2][2];
#pragma unroll
    for (int i = 0; i < 2; ++i)
#pragma unroll
        for (int j = 0; j < 2; ++j) acc[i][j] = (f32x4){0.f, 0.f, 0.f, 0.f};

    bf16x8 b0 = *(const bf16x8*)V0;
    bf16x8 b1 = *(const bf16x8*)V1;
    for (int k0 = 0; k0 < KCAT; k0 += 32) {
        int kn = (k0 + 32 < KCAT) ? k0 + 32 : 0;   // branchless prefetch (last one redundant)
        bf16x8 n0 = *(const bf16x8*)(V0 + kn);
        bf16x8 n1 = *(const bf16x8*)(V1 + kn);
        bf16x8 a0 = *(const bf16x8*)(Ash + (size_t)(wrow + c) * AST + k0 + quad * 8);
        bf16x8 a1 = *(const bf16x8*)(Ash + (size_t)(wrow + 16 + c) * AST + k0 + quad * 8);
        acc[0][0] = __builtin_amdgcn_mfma_f32_16x16x32_bf16(a0, b0, acc[0][0], 0, 0, 0);
        acc[0][1] = __builtin_amdgcn_mfma_f32_16x16x32_bf16(a0, b1, acc[0][1], 0, 0, 0);
        acc[1][0] = __builtin_amdgcn_mfma_f32_16x16x32_bf16(a1, b0, acc[1][0], 0, 0, 0);
        acc[1][1] = __builtin_amdgcn_mfma_f32_16x16x32_bf16(a1, b1, acc[1][1], 0, 0, 0);
        b0 = n0; b1 = n1;
    }

    // epilogue: + bias, ELU, store f32. C/D: col=lane&15, row=quad*4+reg
#pragma unroll
    for (int ri = 0; ri < 2; ++ri) {
#pragma unroll
        for (int ci = 0; ci < 2; ++ci) {
            int col = wcol + ci * 16 + c;
            float bv = bias[col];
#pragma unroll
            for (int reg = 0; reg < 4; ++reg) {
                int grow = base + wrow + ri * 16 + quad * 4 + reg;
                if (grow < N) {
                    float v = acc[ri][ci][reg] + bv;
                    out[(size_t)grow * 128 + col] = (v > 0.f) ? v : expm1f(v);
                }
            }
        }
    }
}

extern "C" void kernel_launch(void* const* d_in, const int* in_sizes, int n_in,
                              void* d_out, int out_size, void* d_ws, size_t ws_size,
                              hipStream_t stream) {
    const float* x  = (const float*)d_in[0];
    const float* Wg = (const float*)d_in[1];
    const float* Wl = (const float*)d_in[2];
    const float* Ws = (const float*)d_in[3];
    const float* b  = (const float*)d_in[4];
    const int*   src = (const int*)d_in[5];
    const int*   dst = (const int*)d_in[6];
    const int*   deg = (const int*)d_in[7];
    const int E = in_sizes[5];
    const int N = in_sizes[7];
    float* out = (float*)d_out;

    unsigned short* V  = (unsigned short*)d_ws;                   // 96 KB
    unsigned short* xb = (unsigned short*)((char*)d_ws + 98304);  // N*128*2 = 12.8 MB

    build_V<<<dim3(128), dim3(KCAT), 0, stream>>>(Wg, Wl, Ws, V);
    int total8 = N * 16;
    convert_x<<<dim3((total8 + 255) / 256), dim3(256), 0, stream>>>(x, xb, total8);
    fused_agg_gemm<<<dim3((N + NPB - 1) / NPB), dim3(512), 0, stream>>>(
        xb, src, dst, deg, V, b, out, N, E);
}